// Round 10
// baseline (713.962 us; speedup 1.0000x reference)
//
#include <hip/hip_runtime.h>

#define N_ 4
#define C_ 128
#define T_ 512
#define V_ 25
#define H_ 16
#define O_ 128
#define VP_ 32        // padded V rows in v workspace (128B)
#define TV_ (T_*V_)   // 12800

#define TT 16         // t-tile per iteration
#define SP 20         // padded S row stride (16+4): 80B, 16B-aligned

// Workspace float offsets
#define WS_XM    0u
#define WS_Q     262144u
#define WS_K     294912u
#define WS_V     327680u       // 4*512*128*32 = 8388608
#define WS_Y0    8716288u      // 6553600 (N*O*T*V) th=0 partial
#define WS_STATS 15269888u     // 256: sum[128], sumsq[128]
#define WS_SC    15270144u     // 128
#define WS_SH    15270272u     // 128
#define WS_END   15270400u
// th=1 partial lives in d_out (fully overwritten each call)

// K0a: xm[n,c,t] = mean over V of x[n,c,t,:]; block 0 also zeroes stats
__global__ void k_xm(const float* __restrict__ x, float* __restrict__ xm,
                     float* __restrict__ stats) {
    int idx = blockIdx.x * 256 + threadIdx.x;        // over N*C*T = 262144
    if (blockIdx.x == 0) stats[threadIdx.x] = 0.f;   // 256 floats
    const float* p = x + (size_t)idx * V_;
    float s = 0.f;
#pragma unroll
    for (int i = 0; i < V_; ++i) s += p[i];
    xm[idx] = s * (1.f / V_);
}

// K0b: q,k[n,h,t] = Wq/Wk @ xm + b
__global__ void k_qk(const float* __restrict__ xm,
                     const float* __restrict__ Wq, const float* __restrict__ bq,
                     const float* __restrict__ Wk, const float* __restrict__ bk,
                     float* __restrict__ q, float* __restrict__ k) {
    int n = blockIdx.x >> 2;             // 4 blocks of 128 t per n
    int t = (blockIdx.x & 3) * 128 + threadIdx.x;
    __shared__ float wq_s[H_ * C_], wk_s[H_ * C_];
    for (int i = threadIdx.x; i < H_ * C_; i += 128) { wq_s[i] = Wq[i]; wk_s[i] = Wk[i]; }
    __syncthreads();
    float qa[H_], ka[H_];
#pragma unroll
    for (int h = 0; h < H_; ++h) { qa[h] = bq[h]; ka[h] = bk[h]; }
    const float* xp = xm + (size_t)n * C_ * T_ + t;
    for (int c = 0; c < C_; ++c) {
        float xv = xp[(size_t)c * T_];
#pragma unroll
        for (int h = 0; h < H_; ++h) {
            qa[h] = fmaf(wq_s[h * C_ + c], xv, qa[h]);
            ka[h] = fmaf(wk_s[h * C_ + c], xv, ka[h]);
        }
    }
#pragma unroll
    for (int h = 0; h < H_; ++h) {
        q[((size_t)n * H_ + h) * T_ + t] = qa[h];
        k[((size_t)n * H_ + h) * T_ + t] = ka[h];
    }
}

// K1: v[n,t,o,vp] = Wv @ x + bv   (layout (n,t,o,VP_), rows padded with zeros)
__global__ void k_v(const float* __restrict__ x, const float* __restrict__ Wv,
                    const float* __restrict__ bv, float* __restrict__ vws) {
    int n = blockIdx.x >> 9;       // 512 t-blocks per n
    int t = blockIdx.x & 511;
    int o = threadIdx.x;           // 128 threads
    __shared__ float xs[C_ * 28];  // padded rows of 28 floats
    for (int i = threadIdx.x; i < C_ * V_; i += 128) {
        int c = i / V_;
        int vi = i - c * V_;
        xs[c * 28 + vi] = x[((size_t)(n * C_ + c) * T_ + t) * V_ + vi];
    }
    __syncthreads();
    float acc[V_];
    float b = bv[o];
#pragma unroll
    for (int i = 0; i < V_; ++i) acc[i] = b;
    for (int c = 0; c < C_; ++c) {
        float w = Wv[o * C_ + c];
        const float4* xr = (const float4*)&xs[c * 28];
#pragma unroll
        for (int u = 0; u < 6; ++u) {
            float4 t4 = xr[u];
            acc[u * 4 + 0] = fmaf(w, t4.x, acc[u * 4 + 0]);
            acc[u * 4 + 1] = fmaf(w, t4.y, acc[u * 4 + 1]);
            acc[u * 4 + 2] = fmaf(w, t4.z, acc[u * 4 + 2]);
            acc[u * 4 + 3] = fmaf(w, t4.w, acc[u * 4 + 3]);
        }
        acc[24] = fmaf(w, xs[c * 28 + 24], acc[24]);
    }
    float* vp = vws + ((size_t)(n * T_ + t) * O_ + o) * VP_;
    float4* vp4 = (float4*)vp;
    float4 w0 = {acc[0], acc[1], acc[2], acc[3]};
    float4 w1 = {acc[4], acc[5], acc[6], acc[7]};
    float4 w2 = {acc[8], acc[9], acc[10], acc[11]};
    float4 w3 = {acc[12], acc[13], acc[14], acc[15]};
    float4 w4 = {acc[16], acc[17], acc[18], acc[19]};
    float4 w5 = {acc[20], acc[21], acc[22], acc[23]};
    float4 w6 = {acc[24], 0.f, 0.f, 0.f};
    float4 w7 = {0.f, 0.f, 0.f, 0.f};
    vp4[0] = w0; vp4[1] = w1; vp4[2] = w2; vp4[3] = w3;
    vp4[4] = w4; vp4[5] = w5; vp4[6] = w6; vp4[7] = w7;
}

// K2: main fused attention kernel, o-blocked + t-split
// grid 1024 blocks (n:4 × gt:32 × ot:4 × th:2), 256 threads -> 4 blocks/CU
// thread = (o_loc = tid>>4, gq = tid&15); owns g = gt*16+gq,
// channels o0 = ot*32+o_loc, o1 = o0+16.  Each S-read feeds 2 o-dots (8 fma).
__global__ __launch_bounds__(256)
void k_main(const float* __restrict__ q, const float* __restrict__ kk,
            const float* __restrict__ vws, const float* __restrict__ Wr,
            const float* __restrict__ br, float* __restrict__ y0,
            float* __restrict__ yout) {
    int b = blockIdx.x;
    int th = b & 1, ot = (b >> 1) & 3, gt = (b >> 3) & 31, n = (b >> 8) & 3;
    int tid = threadIdx.x;
    int gq = tid & 15, o_loc = tid >> 4;         // o_loc in 0..15
    int g = gt * 16 + gq;
    int o0 = ot * 32 + o_loc, o1 = o0 + 16;

    __shared__ float S[H_][16][SP];              // 16*16*20*4 = 20480 B

    float wr0[H_], wr1[H_];
#pragma unroll
    for (int h = 0; h < H_; ++h) {
        wr0[h] = Wr[o0 * H_ + h];
        wr1[h] = Wr[o1 * H_ + h];
    }
    float br0 = br[o0], br1 = br[o1];

    int hA = o_loc;                              // phase-A identity: 16 h values
    float qA = q[((size_t)n * H_ + hA) * T_ + g];
    float e2q = __expf(2.f * qA);                // tanh(q-k) = 1 - 2/(e2q*e^-2k + 1)
    const float* krow = kk + ((size_t)n * H_ + hA) * T_;

    float4 acc0[7], acc1[7];                     // 28 lanes each; 25..27 stay 0
#pragma unroll
    for (int u = 0; u < 7; ++u) {
        acc0[u] = make_float4(0.f, 0.f, 0.f, 0.f);
        acc1[u] = make_float4(0.f, 0.f, 0.f, 0.f);
    }

    const float* vb0 = vws + (size_t)n * T_ * O_ * VP_ + (size_t)o0 * VP_;
    const float* vb1 = vb0 + 16 * VP_;           // o1 = o0 + 16

    for (int tt = th * 16; tt < th * 16 + 16; ++tt) {
        int t0 = tt * TT;
        __syncthreads();   // S consumed by previous phase B
        // Phase A: S[hA][gq][0..15] = tanh(qA - k[t0..t0+15])
        {
            const float4* kp = (const float4*)(krow + t0);
#pragma unroll
            for (int j = 0; j < 4; ++j) {
                float4 kv = kp[j];
                float4 ek;
                ek.x = __expf(-2.f * kv.x);  ek.y = __expf(-2.f * kv.y);
                ek.z = __expf(-2.f * kv.z);  ek.w = __expf(-2.f * kv.w);
                float4 sv;
                sv.x = fmaf(-2.f, __builtin_amdgcn_rcpf(fmaf(e2q, ek.x, 1.f)), 1.f);
                sv.y = fmaf(-2.f, __builtin_amdgcn_rcpf(fmaf(e2q, ek.y, 1.f)), 1.f);
                sv.z = fmaf(-2.f, __builtin_amdgcn_rcpf(fmaf(e2q, ek.z, 1.f)), 1.f);
                sv.w = fmaf(-2.f, __builtin_amdgcn_rcpf(fmaf(e2q, ek.w, 1.f)), 1.f);
                *(float4*)&S[hA][gq][4 * j] = sv;
            }
        }
        __syncthreads();
        // Phase B: A[o] = Wr[o]·S + br[o] for o0,o1; then acc += A * v
#pragma unroll 1
        for (int j4 = 0; j4 < 4; ++j4) {
            float a0[4] = {br0, br0, br0, br0};
            float a1[4] = {br1, br1, br1, br1};
#pragma unroll
            for (int h = 0; h < H_; ++h) {
                float4 s4 = *(const float4*)&S[h][gq][4 * j4];
                float w0 = wr0[h], w1 = wr1[h];
                a0[0] = fmaf(w0, s4.x, a0[0]);
                a0[1] = fmaf(w0, s4.y, a0[1]);
                a0[2] = fmaf(w0, s4.z, a0[2]);
                a0[3] = fmaf(w0, s4.w, a0[3]);
                a1[0] = fmaf(w1, s4.x, a1[0]);
                a1[1] = fmaf(w1, s4.y, a1[1]);
                a1[2] = fmaf(w1, s4.z, a1[2]);
                a1[3] = fmaf(w1, s4.w, a1[3]);
            }
#pragma unroll
            for (int r = 0; r < 4; ++r) {
                size_t toff = (size_t)(t0 + j4 * 4 + r) * O_ * VP_;
                const float4* vp0 = (const float4*)(vb0 + toff);
                const float4* vp1 = (const float4*)(vb1 + toff);
                float A0 = a0[r], A1 = a1[r];
#pragma unroll
                for (int u = 0; u < 7; ++u) {
                    float4 v0 = vp0[u];
                    float4 v1 = vp1[u];
                    acc0[u].x = fmaf(A0, v0.x, acc0[u].x);
                    acc0[u].y = fmaf(A0, v0.y, acc0[u].y);
                    acc0[u].z = fmaf(A0, v0.z, acc0[u].z);
                    acc0[u].w = fmaf(A0, v0.w, acc0[u].w);
                    acc1[u].x = fmaf(A1, v1.x, acc1[u].x);
                    acc1[u].y = fmaf(A1, v1.y, acc1[u].y);
                    acc1[u].z = fmaf(A1, v1.z, acc1[u].z);
                    acc1[u].w = fmaf(A1, v1.w, acc1[u].w);
                }
            }
        }
    }

    // write y partial (pre-BN), layout (n,o,g,v) — component-wise only
    float* yb = (th == 0) ? y0 : yout;
    float* yp0 = yb + (((size_t)(n * O_ + o0)) * T_ + g) * V_;
    float* yp1 = yb + (((size_t)(n * O_ + o1)) * T_ + g) * V_;
#pragma unroll
    for (int u = 0; u < 6; ++u) {
        yp0[4 * u + 0] = acc0[u].x;  yp0[4 * u + 1] = acc0[u].y;
        yp0[4 * u + 2] = acc0[u].z;  yp0[4 * u + 3] = acc0[u].w;
        yp1[4 * u + 0] = acc1[u].x;  yp1[4 * u + 1] = acc1[u].y;
        yp1[4 * u + 2] = acc1[u].z;  yp1[4 * u + 3] = acc1[u].w;
    }
    yp0[24] = acc0[6].x;
    yp1[24] = acc1[6].x;
}

// K2b: BN stats from y = y0 + y1 (no write-back; k_bnout re-adds).
// Each 64-lane wave lies within one (n,o) row (3200 quads/row, 3200 % 64 == 0).
__global__ void k_sum(const float* __restrict__ y0, const float* __restrict__ y1,
                      float* __restrict__ stats) {
    int q4 = blockIdx.x * 256 + threadIdx.x;    // over 1638400 quads
    int o = (q4 / (TV_ / 4)) & (O_ - 1);        // uniform within a wave
    float4 a = ((const float4*)y0)[q4];
    float4 bb = ((const float4*)y1)[q4];
    float4 s;
    s.x = a.x + bb.x;  s.y = a.y + bb.y;
    s.z = a.z + bb.z;  s.w = a.w + bb.w;
    float s1 = s.x + s.y + s.z + s.w;
    float s2 = s.x * s.x;
    s2 = fmaf(s.y, s.y, s2);
    s2 = fmaf(s.z, s.z, s2);
    s2 = fmaf(s.w, s.w, s2);
#pragma unroll
    for (int m = 32; m > 0; m >>= 1) {
        s1 += __shfl_xor(s1, m);
        s2 += __shfl_xor(s2, m);
    }
    if ((threadIdx.x & 63) == 0) {
        atomicAdd(stats + o, s1);
        atomicAdd(stats + O_ + o, s2);
    }
}

// K3: finalize BN stats -> scale/shift
__global__ void k_stats(const float* __restrict__ stats,
                        const float* __restrict__ gamma, const float* __restrict__ beta,
                        float* __restrict__ sc, float* __restrict__ sh) {
    int o = threadIdx.x;   // 128
    const float invM = 1.f / (float)(N_ * T_ * V_);
    float mean = stats[o] * invM;
    float var = stats[O_ + o] * invM - mean * mean;
    float rstd = rsqrtf(var + 1e-5f);
    float s = gamma[o] * rstd;
    sc[o] = s;
    sh[o] = beta[o] - mean * s;
}

// K4: out = relu((y0+y1)*sc[o] + sh[o] + x); y1 aliases out (read-then-write).
__global__ void k_bnout(const float* __restrict__ y0, const float* __restrict__ y1,
                        const float* __restrict__ x,
                        const float* __restrict__ sc, const float* __restrict__ sh,
                        float* __restrict__ out) {
    int q4 = blockIdx.x * 256 + threadIdx.x;   // 1638400 quads
    int row = q4 / (TV_ / 4);                  // n*O_+o  (TV_/4 = 3200)
    int o = row & (O_ - 1);
    float4 ya = ((const float4*)y0)[q4];
    float4 yb = ((const float4*)y1)[q4];
    float4 xv = ((const float4*)x)[q4];
    float s = sc[o], b = sh[o];
    float4 r;
    r.x = fmaxf(fmaf(ya.x + yb.x, s, b) + xv.x, 0.f);
    r.y = fmaxf(fmaf(ya.y + yb.y, s, b) + xv.y, 0.f);
    r.z = fmaxf(fmaf(ya.z + yb.z, s, b) + xv.z, 0.f);
    r.w = fmaxf(fmaf(ya.w + yb.w, s, b) + xv.w, 0.f);
    ((float4*)out)[q4] = r;
}

extern "C" void kernel_launch(void* const* d_in, const int* in_sizes, int n_in,
                              void* d_out, int out_size, void* d_ws, size_t ws_size,
                              hipStream_t stream) {
    const float* x     = (const float*)d_in[0];
    const float* Wq    = (const float*)d_in[1];
    const float* bq    = (const float*)d_in[2];
    const float* Wk    = (const float*)d_in[3];
    const float* bk    = (const float*)d_in[4];
    const float* Wv    = (const float*)d_in[5];
    const float* bv    = (const float*)d_in[6];
    const float* Wr    = (const float*)d_in[7];
    const float* br    = (const float*)d_in[8];
    const float* gamma = (const float*)d_in[9];
    const float* beta  = (const float*)d_in[10];
    float* out = (float*)d_out;
    float* ws  = (float*)d_ws;

    if (ws_size < (size_t)WS_END * sizeof(float)) return;  // insufficient scratch

    float* xm    = ws + WS_XM;
    float* q     = ws + WS_Q;
    float* k     = ws + WS_K;
    float* vws   = ws + WS_V;
    float* y0    = ws + WS_Y0;
    float* stats = ws + WS_STATS;
    float* sc    = ws + WS_SC;
    float* sh    = ws + WS_SH;

    k_xm<<<1024, 256, 0, stream>>>(x, xm, stats);
    k_qk<<<16, 128, 0, stream>>>(xm, Wq, bq, Wk, bk, q, k);
    k_v<<<2048, 128, 0, stream>>>(x, Wv, bv, vws);
    k_main<<<1024, 256, 0, stream>>>(q, k, vws, Wr, br, y0, out);  // th=1 -> out
    k_sum<<<6400, 256, 0, stream>>>(y0, out, stats);
    k_stats<<<1, 128, 0, stream>>>(stats, gamma, beta, sc, sh);
    k_bnout<<<6400, 256, 0, stream>>>(y0, out, x, sc, sh, out);
}

// Round 11
// 333.457 us; speedup vs baseline: 2.1411x; 2.1411x over previous
//
#include <hip/hip_runtime.h>

#define N_ 4
#define C_ 128
#define T_ 512
#define V_ 25
#define H_ 16
#define O_ 128
#define TV_ (T_*V_)   // 12800

typedef __attribute__((ext_vector_type(8)))  short short8;
typedef __attribute__((ext_vector_type(16))) float f32x16;

// Workspace float offsets (within proven 15,270,400-float footprint)
#define WS_XM    0u         // 262144 floats
#define WS_Q     262144u    // 32768
#define WS_K     294912u    // 32768
#define WS_V     327680u    // vws fp32 (n,t,o,32): 8,388,608 floats -> ends 8,716,288
#define WS_Y     327680u    // y (6,553,600 floats) ALIASES vws: vws dead after k_vt
#define WS_VB    8716288u   // vbf u16 (n,o,32,t): 8,388,608 u16 = 4,194,304 float slots
#define WS_STATS 15269888u  // 256
#define WS_SC    15270144u
#define WS_SH    15270272u
#define WS_END   15270400u

__device__ __forceinline__ unsigned short f2bf(float f) {
    unsigned u = __float_as_uint(f);
    u += 0x7fffu + ((u >> 16) & 1u);   // RNE
    return (unsigned short)(u >> 16);
}

// K0a: xm[n,c,t] = mean over V of x; block 0 zeroes stats
__global__ void k_xm(const float* __restrict__ x, float* __restrict__ xm,
                     float* __restrict__ stats) {
    int idx = blockIdx.x * 256 + threadIdx.x;
    if (blockIdx.x == 0) stats[threadIdx.x] = 0.f;
    const float* p = x + (size_t)idx * V_;
    float s = 0.f;
#pragma unroll
    for (int i = 0; i < V_; ++i) s += p[i];
    xm[idx] = s * (1.f / V_);
}

// K0b: q,k[n,h,t] = Wq/Wk @ xm + b
__global__ void k_qk(const float* __restrict__ xm,
                     const float* __restrict__ Wq, const float* __restrict__ bq,
                     const float* __restrict__ Wk, const float* __restrict__ bk,
                     float* __restrict__ q, float* __restrict__ k) {
    int n = blockIdx.x >> 2;
    int t = (blockIdx.x & 3) * 128 + threadIdx.x;
    __shared__ float wq_s[H_ * C_], wk_s[H_ * C_];
    for (int i = threadIdx.x; i < H_ * C_; i += 128) { wq_s[i] = Wq[i]; wk_s[i] = Wk[i]; }
    __syncthreads();
    float qa[H_], ka[H_];
#pragma unroll
    for (int h = 0; h < H_; ++h) { qa[h] = bq[h]; ka[h] = bk[h]; }
    const float* xp = xm + (size_t)n * C_ * T_ + t;
    for (int c = 0; c < C_; ++c) {
        float xv = xp[(size_t)c * T_];
#pragma unroll
        for (int h = 0; h < H_; ++h) {
            qa[h] = fmaf(wq_s[h * C_ + c], xv, qa[h]);
            ka[h] = fmaf(wk_s[h * C_ + c], xv, ka[h]);
        }
    }
#pragma unroll
    for (int h = 0; h < H_; ++h) {
        q[((size_t)n * H_ + h) * T_ + t] = qa[h];
        k[((size_t)n * H_ + h) * T_ + t] = ka[h];
    }
}

// K1: vws[n,t,o,32] fp32 = Wv @ x + bv (pad lanes 25..31 zero)
__global__ void k_v(const float* __restrict__ x, const float* __restrict__ Wv,
                    const float* __restrict__ bv, float* __restrict__ vws) {
    int n = blockIdx.x >> 9;
    int t = blockIdx.x & 511;
    int o = threadIdx.x;
    __shared__ float xs[C_ * 28];
    for (int i = threadIdx.x; i < C_ * V_; i += 128) {
        int c = i / V_;
        int vi = i - c * V_;
        xs[c * 28 + vi] = x[((size_t)(n * C_ + c) * T_ + t) * V_ + vi];
    }
    __syncthreads();
    float acc[V_];
    float b = bv[o];
#pragma unroll
    for (int i = 0; i < V_; ++i) acc[i] = b;
    for (int c = 0; c < C_; ++c) {
        float w = Wv[o * C_ + c];
        const float4* xr = (const float4*)&xs[c * 28];
#pragma unroll
        for (int u = 0; u < 6; ++u) {
            float4 t4 = xr[u];
            acc[u * 4 + 0] = fmaf(w, t4.x, acc[u * 4 + 0]);
            acc[u * 4 + 1] = fmaf(w, t4.y, acc[u * 4 + 1]);
            acc[u * 4 + 2] = fmaf(w, t4.z, acc[u * 4 + 2]);
            acc[u * 4 + 3] = fmaf(w, t4.w, acc[u * 4 + 3]);
        }
        acc[24] = fmaf(w, xs[c * 28 + 24], acc[24]);
    }
    float* vp = vws + ((size_t)(n * T_ + t) * O_ + o) * 32;
    float4* vp4 = (float4*)vp;
    float4 w0 = {acc[0], acc[1], acc[2], acc[3]};
    float4 w1 = {acc[4], acc[5], acc[6], acc[7]};
    float4 w2 = {acc[8], acc[9], acc[10], acc[11]};
    float4 w3 = {acc[12], acc[13], acc[14], acc[15]};
    float4 w4 = {acc[16], acc[17], acc[18], acc[19]};
    float4 w5 = {acc[20], acc[21], acc[22], acc[23]};
    float4 w6 = {acc[24], 0.f, 0.f, 0.f};
    float4 w7 = {0.f, 0.f, 0.f, 0.f};
    vp4[0] = w0; vp4[1] = w1; vp4[2] = w2; vp4[3] = w3;
    vp4[4] = w4; vp4[5] = w5; vp4[6] = w6; vp4[7] = w7;
}

// K1b: transpose vws(n,t,o,32) fp32 -> vbf(n,o,32,t) bf16 via LDS tile
// grid 512 = n4 x tt8(64 t) x og16(8 o); 256 threads
__global__ void k_vt(const float* __restrict__ vws, unsigned short* __restrict__ vbf) {
    int b = blockIdx.x;
    int n = b >> 7, tt = (b >> 4) & 7, og = b & 15;
    int tid = threadIdx.x;
    __shared__ float ld[64 * 257];
    // read: per t-row, 256 consecutive floats (o-group 8 x vv 32)
    for (int it = 0; it < 64; ++it) {
        int t = tt * 64 + it;
        ld[it * 257 + tid] = vws[(size_t)(n * T_ + t) * (O_ * 32) + og * 256 + tid];
    }
    __syncthreads();
    // write: lane = t (coalesced u16), pair p = (oL, vv)
    int tl = tid & 63;
    int pbase = tid >> 6;          // 0..3
    for (int it = 0; it < 64; ++it) {
        int p = pbase + it * 4;    // 0..255
        int oL = p >> 5, vv = p & 31;
        int o = og * 8 + oL;
        float val = ld[tl * 257 + p];
        vbf[((size_t)(n * O_ + o) * 32 + vv) * T_ + tt * 64 + tl] = f2bf(val);
    }
}

// K2: MFMA main kernel. grid 256 = n4 x gt16 x ot4; 512 threads (8 waves)
// LDS: S_bf[g32][t32][h16] bf16 @0 (32KB, XOR (g&7)<<4)
//      A_bf[o32][g32][t32] bf16 @32768 (64KB, XOR ((o^g)&7)<<4)
__global__ __launch_bounds__(512)
void k_main(const float* __restrict__ q, const float* __restrict__ kk,
            const unsigned short* __restrict__ vbf,
            const float* __restrict__ Wr, const float* __restrict__ br,
            float* __restrict__ y, float* __restrict__ stats) {
    extern __shared__ char smem[];
    char* S_base = smem;
    char* A_base = smem + 32768;

    int b = blockIdx.x;
    int n = b >> 6, gt = (b >> 2) & 15, ot = b & 3;
    int g_base = gt * 32, o_base = ot * 32;
    int tid = threadIdx.x;
    int lane = tid & 63;
    int w = tid >> 6;            // wave 0..7
    int l31 = lane & 31;
    int lhi = lane >> 5;         // 0/1

    // phase-A thread identity: g = gA, t = tqA / tqA+16 within tile
    int gA = tid & 31;
    int tqA = tid >> 5;          // 0..15
    float e2q[16];
    {
        const float* qp = q + (size_t)n * H_ * T_ + g_base + gA;
#pragma unroll
        for (int h = 0; h < 16; ++h) e2q[h] = __expf(2.f * qp[(size_t)h * T_]);
    }
    const float* krow = kk + (size_t)n * H_ * T_;

    // Wr B-frag for MFMA-1: lane: col o = o_base+l31, k h = lhi*8 + i
    short8 wrb;
    {
        const float* wp = Wr + (size_t)(o_base + l31) * H_ + lhi * 8;
        unsigned u0, u1, u2, u3;
        asm("v_cvt_pk_bf16_f32 %0, %1, %2" : "=v"(u0) : "v"(wp[0]), "v"(wp[1]));
        asm("v_cvt_pk_bf16_f32 %0, %1, %2" : "=v"(u1) : "v"(wp[2]), "v"(wp[3]));
        asm("v_cvt_pk_bf16_f32 %0, %1, %2" : "=v"(u2) : "v"(wp[4]), "v"(wp[5]));
        asm("v_cvt_pk_bf16_f32 %0, %1, %2" : "=v"(u3) : "v"(wp[6]), "v"(wp[7]));
        union { uint4 u; short8 s; } cv;
        cv.u = make_uint4(u0, u1, u2, u3);
        wrb = cv.s;
    }
    float brv = br[o_base + l31];

    f32x16 acc[4];
#pragma unroll
    for (int j = 0; j < 4; ++j)
#pragma unroll
        for (int r = 0; r < 16; ++r) acc[j][r] = 0.f;

    const unsigned short* vb_n = vbf + (size_t)n * O_ * 32 * T_;

    for (int tt = 0; tt < 16; ++tt) {
        int t0 = tt * 32;
        // ---- phase A: S tile (tanh) ----
#pragma unroll
        for (int p = 0; p < 2; ++p) {
            int tcur = tqA + p * 16;
            int tg = t0 + tcur;
            unsigned pk_[8];
#pragma unroll
            for (int i2 = 0; i2 < 8; ++i2) {
                float ek0 = __expf(-2.f * krow[(size_t)(2 * i2) * T_ + tg]);
                float ek1 = __expf(-2.f * krow[(size_t)(2 * i2 + 1) * T_ + tg]);
                float sa = fmaf(-2.f, __builtin_amdgcn_rcpf(fmaf(e2q[2 * i2], ek0, 1.f)), 1.f);
                float sb = fmaf(-2.f, __builtin_amdgcn_rcpf(fmaf(e2q[2 * i2 + 1], ek1, 1.f)), 1.f);
                asm("v_cvt_pk_bf16_f32 %0, %1, %2" : "=v"(pk_[i2]) : "v"(sa), "v"(sb));
            }
            unsigned sb0 = (unsigned)(gA * 1024 + tcur * 32);
            unsigned xr = (unsigned)(gA & 7) << 4;
            *(uint4*)(S_base + ((sb0 + 0) ^ xr)) = make_uint4(pk_[0], pk_[1], pk_[2], pk_[3]);
            *(uint4*)(S_base + ((sb0 + 16) ^ xr)) = make_uint4(pk_[4], pk_[5], pk_[6], pk_[7]);
        }
        __syncthreads();
        // ---- MFMA-1: D1[t][o] = S[t][h] x Wr^T[h][o], per g; -> A_bf ----
#pragma unroll
        for (int i = 0; i < 4; ++i) {
            int g = w * 4 + i;
            unsigned saddr = ((unsigned)(g * 1024 + l31 * 32 + lhi * 16)) ^ ((unsigned)(g & 7) << 4);
            short8 sfrag = *(const short8*)(S_base + saddr);
            f32x16 zz;
#pragma unroll
            for (int r = 0; r < 16; ++r) zz[r] = 0.f;
            f32x16 d1 = __builtin_amdgcn_mfma_f32_32x32x16_bf16(sfrag, wrb, zz, 0, 0, 0);
            unsigned xo = (unsigned)(((l31 ^ g) & 7) << 4);
#pragma unroll
            for (int rq = 0; rq < 4; ++rq) {
                float c0 = d1[4 * rq + 0] + brv;
                float c1 = d1[4 * rq + 1] + brv;
                float c2 = d1[4 * rq + 2] + brv;
                float c3 = d1[4 * rq + 3] + brv;
                unsigned p0, p1;
                asm("v_cvt_pk_bf16_f32 %0, %1, %2" : "=v"(p0) : "v"(c0), "v"(c1));
                asm("v_cvt_pk_bf16_f32 %0, %1, %2" : "=v"(p1) : "v"(c2), "v"(c3));
                int tpr = 8 * rq + 4 * lhi;    // D row = t'
                unsigned aaddr = ((unsigned)(l31 * 2048 + g * 64 + tpr * 2)) ^ xo;
                *(uint2*)(A_base + aaddr) = make_uint2(p0, p1);
            }
        }
        __syncthreads();
        // ---- MFMA-2: D2[g][v] += A[g][t16] x v[t16][v], per o ----
#pragma unroll
        for (int j = 0; j < 4; ++j) {
            int ol = w * 4 + j;
            int o = o_base + ol;
            const unsigned short* vrow =
                vb_n + ((size_t)o * 32 + l31) * T_ + t0 + lhi * 8;
            unsigned xa = (unsigned)(((ol ^ l31) & 7) << 4);
#pragma unroll
            for (int tc = 0; tc < 2; ++tc) {
                unsigned aaddr = ((unsigned)(ol * 2048 + l31 * 64 + (tc * 16 + lhi * 8) * 2)) ^ xa;
                short8 afrag = *(const short8*)(A_base + aaddr);
                short8 vfrag = *(const short8*)(vrow + tc * 16);
                acc[j] = __builtin_amdgcn_mfma_f32_32x32x16_bf16(afrag, vfrag, acc[j], 0, 0, 0);
            }
        }
        __syncthreads();
    }

    // ---- epilogue: y write + BN stats ----
#pragma unroll
    for (int j = 0; j < 4; ++j) {
        int o = o_base + w * 4 + j;
        float s1 = 0.f, s2 = 0.f;
        float* yrow = y + ((size_t)(n * O_ + o) * T_ + g_base) * V_;
#pragma unroll
        for (int r = 0; r < 16; ++r) {
            int gp = (r & 3) + 8 * (r >> 2) + 4 * lhi;   // D row = g'
            float val = acc[j][r];
            s1 += val;
            s2 = fmaf(val, val, s2);
            if (l31 < 25) yrow[gp * V_ + l31] = val;     // v>=25 cols are exact zeros
        }
#pragma unroll
        for (int m = 1; m < 64; m <<= 1) {
            s1 += __shfl_xor(s1, m);
            s2 += __shfl_xor(s2, m);
        }
        if (lane == 0) {
            atomicAdd(stats + o, s1);
            atomicAdd(stats + O_ + o, s2);
        }
    }
}

// K3: finalize BN stats
__global__ void k_stats(const float* __restrict__ stats,
                        const float* __restrict__ gamma, const float* __restrict__ beta,
                        float* __restrict__ sc, float* __restrict__ sh) {
    int o = threadIdx.x;
    const float invM = 1.f / (float)(N_ * T_ * V_);
    float mean = stats[o] * invM;
    float var = stats[O_ + o] * invM - mean * mean;
    float rstd = rsqrtf(var + 1e-5f);
    float s = gamma[o] * rstd;
    sc[o] = s;
    sh[o] = beta[o] - mean * s;
}

// K4: out = relu(y*sc + sh + x)
__global__ void k_bnout(const float* __restrict__ y, const float* __restrict__ x,
                        const float* __restrict__ sc, const float* __restrict__ sh,
                        float* __restrict__ out) {
    int q4 = blockIdx.x * 256 + threadIdx.x;
    int row = q4 / (TV_ / 4);
    int o = row & (O_ - 1);
    float4 yv = ((const float4*)y)[q4];
    float4 xv = ((const float4*)x)[q4];
    float s = sc[o], b = sh[o];
    float4 r;
    r.x = fmaxf(fmaf(yv.x, s, b) + xv.x, 0.f);
    r.y = fmaxf(fmaf(yv.y, s, b) + xv.y, 0.f);
    r.z = fmaxf(fmaf(yv.z, s, b) + xv.z, 0.f);
    r.w = fmaxf(fmaf(yv.w, s, b) + xv.w, 0.f);
    ((float4*)out)[q4] = r;
}

extern "C" void kernel_launch(void* const* d_in, const int* in_sizes, int n_in,
                              void* d_out, int out_size, void* d_ws, size_t ws_size,
                              hipStream_t stream) {
    const float* x     = (const float*)d_in[0];
    const float* Wq    = (const float*)d_in[1];
    const float* bq    = (const float*)d_in[2];
    const float* Wk    = (const float*)d_in[3];
    const float* bk    = (const float*)d_in[4];
    const float* Wv    = (const float*)d_in[5];
    const float* bv    = (const float*)d_in[6];
    const float* Wr    = (const float*)d_in[7];
    const float* br    = (const float*)d_in[8];
    const float* gamma = (const float*)d_in[9];
    const float* beta  = (const float*)d_in[10];
    float* out = (float*)d_out;
    float* ws  = (float*)d_ws;

    if (ws_size < (size_t)WS_END * sizeof(float)) return;

    float* xm    = ws + WS_XM;
    float* q     = ws + WS_Q;
    float* k     = ws + WS_K;
    float* vws   = ws + WS_V;
    float* y     = ws + WS_Y;                 // aliases vws (dead after k_vt)
    unsigned short* vbf = (unsigned short*)(ws + WS_VB);
    float* stats = ws + WS_STATS;
    float* sc    = ws + WS_SC;
    float* sh    = ws + WS_SH;

    k_xm<<<1024, 256, 0, stream>>>(x, xm, stats);
    k_qk<<<16, 128, 0, stream>>>(xm, Wq, bq, Wk, bk, q, k);
    k_v<<<2048, 128, 0, stream>>>(x, Wv, bv, vws);
    k_vt<<<512, 256, 0, stream>>>(vws, vbf);
    k_main<<<256, 512, 98304, stream>>>(q, k, vbf, Wr, br, y, stats);
    k_stats<<<1, 128, 0, stream>>>(stats, gamma, beta, sc, sh);
    k_bnout<<<6400, 256, 0, stream>>>(y, x, sc, sh, out);
}